// Round 7
// baseline (2562.347 us; speedup 1.0000x reference)
//
#include <hip/hip_runtime.h>

// GRU classifier: x[256,512,128] -> GRU(H=512) -> head -> out[256,1000]
// R4: 128 persistent blocks (16 groups x 8 blocks, 64 cols/block), weights in
// VGPRs, h exchanged in MFMA-fragment layout via IC (relaxed agent atomics),
// LDS-staged once per block; per-block flag barrier (no RMW contention).

#define NB 256
#define NH 512
#define NI 128
#define NC 1000
#define NS 512

typedef __attribute__((ext_vector_type(8))) short bf16x8;
typedef __attribute__((ext_vector_type(4))) float f32x4;

__device__ __forceinline__ unsigned short f2bf(float f) {
    unsigned u = __builtin_bit_cast(unsigned, f);
    return (unsigned short)((u + 0x7FFFu + ((u >> 16) & 1u)) >> 16);  // RNE
}

__device__ __forceinline__ bf16x8 pack8(const float* v) {
    bf16x8 r;
#pragma unroll
    for (int i = 0; i < 8; ++i) r[i] = (short)f2bf(v[i]);
    return r;
}

__device__ __forceinline__ unsigned long long ld_agent_u64(const unsigned long long* p) {
    return __hip_atomic_load(p, __ATOMIC_RELAXED, __HIP_MEMORY_SCOPE_AGENT);
}
__device__ __forceinline__ unsigned int ld_agent_u32(const unsigned int* p) {
    return __hip_atomic_load(p, __ATOMIC_RELAXED, __HIP_MEMORY_SCOPE_AGENT);
}
__device__ __forceinline__ void st_agent_u16(unsigned short* p, unsigned short v) {
    __hip_atomic_store(p, v, __ATOMIC_RELAXED, __HIP_MEMORY_SCOPE_AGENT);
}
__device__ __forceinline__ void st_agent_u32(unsigned int* p, unsigned int v) {
    __hip_atomic_store(p, v, __ATOMIC_RELAXED, __HIP_MEMORY_SCOPE_AGENT);
}

// zero the 512 flag words (plain stores; kernel-boundary flush makes them
// IC-visible to the scan's sc1 reads). hbuf needs no init (t=0 writes buf1).
__global__ void gru_init_ws(unsigned int* __restrict__ fl) {
    const int i = blockIdx.x * 256 + threadIdx.x;
    if (i < 512) fl[i] = 0u;
}

// 128 blocks x 256 threads. g=bid&15 (rows 16g..16g+16), jb=bid>>4 (0..7,
// cols 64jb..64jb+64). Wave w owns 16 cols (jb*64+w*16). Full K=512 per wave.
// hbuf layout: [2][16 g][16 frag][512] bf16; frag = A-fragment of 16 rows x
// 32 k: elem(lane l, e) = h[row=l&15][k=frag*32+(l>>4)*8+e].
__global__ void __launch_bounds__(256, 1) gru_scan(
    const float* __restrict__ x,
    const float* __restrict__ Wih,
    const float* __restrict__ Whh,
    const float* __restrict__ bih,
    const float* __restrict__ bhh,
    unsigned short* __restrict__ hbuf,
    float* __restrict__ hT,
    unsigned int* __restrict__ flags)    // [16 groups][32] u32 (128B stride)
{
    const int tid = threadIdx.x;
    const int l   = tid & 63;
    const int w   = tid >> 6;
    const int l15 = l & 15;
    const int lq  = l >> 4;
    const int bid = blockIdx.x;
    const int g   = bid & 15;
    const int jb  = bid >> 4;
    const int c   = jb * 64 + w * 16 + l15;   // this lane's output col

    __shared__ __align__(16) unsigned short hstage[16 * 512];  // 16KB

    // ---- weights -> bf16 fragments in VGPRs ----
    // B-frag (16x16x32): lane holds W[col=l&15 of wave tile][k=(l>>4)*8+0..7]
    bf16x8 whh[3][16];
#pragma unroll
    for (int gt = 0; gt < 3; ++gt) {
        const float* wr = Whh + (size_t)(gt * NH + c) * NH;
#pragma unroll
        for (int ks = 0; ks < 16; ++ks) {
            float tmp[8];
            *(f32x4*)(tmp)     = *(const f32x4*)(wr + ks * 32 + lq * 8);
            *(f32x4*)(tmp + 4) = *(const f32x4*)(wr + ks * 32 + lq * 8 + 4);
            whh[gt][ks] = pack8(tmp);
        }
    }
    bf16x8 wih[3][4];
#pragma unroll
    for (int gt = 0; gt < 3; ++gt) {
        const float* wr = Wih + (size_t)(gt * NH + c) * NI;
#pragma unroll
        for (int ks = 0; ks < 4; ++ks) {
            float tmp[8];
            *(f32x4*)(tmp)     = *(const f32x4*)(wr + ks * 32 + lq * 8);
            *(f32x4*)(tmp + 4) = *(const f32x4*)(wr + ks * 32 + lq * 8 + 4);
            wih[gt][ks] = pack8(tmp);
        }
    }

    const float bR = bih[c] + bhh[c];
    const float bZ = bih[NH + c] + bhh[NH + c];
    const float bNx = bih[2 * NH + c];
    const float bNh = bhh[2 * NH + c];

    float hprev[4] = {0.f, 0.f, 0.f, 0.f};  // rows lq*4+0..3, col c

    const float* xrow = x + (size_t)(g * 16 + l15) * (NS * NI) + lq * 8;
    unsigned int* fl = flags + g * 32;

    // producer-side store mapping (into fragment layout)
    const int Fst   = jb * 2 + (w >> 1);                       // frag index
    const int lanep = ((w & 1) * 2 + (l15 >> 3)) * 16;         // lane' base
    const int est   = l15 & 7;                                 // elem

    for (int t = 0; t < NS; ++t) {
        const int rb = t & 1, wb = rb ^ 1;

        if (t > 0) {
            // ---- group barrier: poll 8 per-block flags (coalesced) ----
            unsigned int myf;
            do { myf = ld_agent_u32(fl + (l & 7)); }
            while (!__all((int)(myf >= (unsigned)t)));
            __builtin_amdgcn_sched_barrier(0);
            asm volatile("" ::: "memory");

            // ---- stage this group's h into LDS (wave w: frags 4w..4w+4) ----
            unsigned long long q0[4], q1[4];
#pragma unroll
            for (int j = 0; j < 4; ++j) {
                const int f = w * 4 + j;
                const unsigned long long* p =
                    (const unsigned long long*)(hbuf + (((size_t)rb * 16 + g) * 16 + f) * 512) + (l << 1);
                q0[j] = ld_agent_u64(p);
                q1[j] = ld_agent_u64(p + 1);
            }
#pragma unroll
            for (int j = 0; j < 4; ++j) {
                const int f = w * 4 + j;
                union { unsigned long long q[2]; bf16x8 v; } u;
                u.q[0] = q0[j]; u.q[1] = q1[j];
                *(bf16x8*)&hstage[f * 512 + l * 8] = u.v;
            }
        }

        // ---- x fragments (plain loads, L1/L2-cached) + x-projection ----
        bf16x8 xf[4];
        {
            const float* xt = xrow + t * NI;
#pragma unroll
            for (int ks = 0; ks < 4; ++ks) {
                float tmp[8];
                *(f32x4*)(tmp)     = *(const f32x4*)(xt + ks * 32);
                *(f32x4*)(tmp + 4) = *(const f32x4*)(xt + ks * 32 + 4);
                xf[ks] = pack8(tmp);
            }
        }
        f32x4 aR  = {bR, bR, bR, bR};
        f32x4 aZ  = {bZ, bZ, bZ, bZ};
        f32x4 aNx = {bNx, bNx, bNx, bNx};
        f32x4 aNh = {bNh, bNh, bNh, bNh};
#pragma unroll
        for (int ks = 0; ks < 4; ++ks) {
            aR  = __builtin_amdgcn_mfma_f32_16x16x32_bf16(xf[ks], wih[0][ks], aR, 0, 0, 0);
            aZ  = __builtin_amdgcn_mfma_f32_16x16x32_bf16(xf[ks], wih[1][ks], aZ, 0, 0, 0);
            aNx = __builtin_amdgcn_mfma_f32_16x16x32_bf16(xf[ks], wih[2][ks], aNx, 0, 0, 0);
        }

        if (t > 0) {
            __syncthreads();  // stage writes -> visible to all waves
#pragma unroll
            for (int ks = 0; ks < 16; ++ks) {
                const bf16x8 af = *(const bf16x8*)&hstage[ks * 512 + l * 8];
                aR  = __builtin_amdgcn_mfma_f32_16x16x32_bf16(af, whh[0][ks], aR, 0, 0, 0);
                aZ  = __builtin_amdgcn_mfma_f32_16x16x32_bf16(af, whh[1][ks], aZ, 0, 0, 0);
                aNh = __builtin_amdgcn_mfma_f32_16x16x32_bf16(af, whh[2][ks], aNh, 0, 0, 0);
            }
        }

        // ---- gates (fp32, in-lane) ----
        float hnew[4];
#pragma unroll
        for (int i = 0; i < 4; ++i) {
            const float rr = __builtin_amdgcn_rcpf(1.f + __expf(-aR[i]));
            const float zz = __builtin_amdgcn_rcpf(1.f + __expf(-aZ[i]));
            const float a  = aNx[i] + rr * aNh[i];
            const float e2 = __expf(2.f * a);
            const float nn = (e2 - 1.f) * __builtin_amdgcn_rcpf(e2 + 1.f);
            hnew[i] = (1.f - zz) * nn + zz * hprev[i];
            hprev[i] = hnew[i];
        }

        if (t < NS - 1) {
            // ---- publish h(t+1) in fragment layout (sc1 -> IC) ----
            unsigned short* dst = hbuf + (((size_t)wb * 16 + g) * 16 + Fst) * 512;
#pragma unroll
            for (int i = 0; i < 4; ++i) {
                const int rl = lq * 4 + i;
                st_agent_u16(dst + (lanep + rl) * 8 + est, f2bf(hnew[i]));
            }
            asm volatile("s_waitcnt vmcnt(0)" ::: "memory");  // stores ack'd at IC
            __syncthreads();                                  // whole block done (incl. LDS reads)
            if (tid == 0) st_agent_u32(&fl[jb], (unsigned)(t + 1));
        } else {
            // final state -> hT (fp32, plain stores; flushed at kernel end)
#pragma unroll
            for (int i = 0; i < 4; ++i)
                hT[(size_t)(g * 16 + lq * 4 + i) * NH + c] = hnew[i];
        }
    }
}

// out[256,1000] = hT[256,512] @ W_head^T + b_head, pure fp32.
__global__ void __launch_bounds__(256, 1) gru_head(
    const float* __restrict__ hT,
    const float* __restrict__ Wh,
    const float* __restrict__ bh,
    float* __restrict__ out)
{
    __shared__ float hs[16 * 512];
    const int tid = threadIdx.x;
    const int rg  = blockIdx.x;
    const int cgp = blockIdx.y;
    const float* src = hT + rg * (16 * 512);
#pragma unroll
    for (int i = 0; i < 32; ++i) hs[tid + 256 * i] = src[tid + 256 * i];
    __syncthreads();
    const int col = (cgp << 6) + (tid & 63);
    const int rb  = (tid >> 6) << 2;
    if (col < NC) {
        const float* wr = Wh + col * NH;
        float a0 = 0.f, a1 = 0.f, a2 = 0.f, a3 = 0.f;
        for (int k = 0; k < NH; k += 4) {
            const f32x4 wv = *(const f32x4*)(wr + k);
            const f32x4 h0 = *(const f32x4*)&hs[(rb + 0) * NH + k];
            const f32x4 h1 = *(const f32x4*)&hs[(rb + 1) * NH + k];
            const f32x4 h2 = *(const f32x4*)&hs[(rb + 2) * NH + k];
            const f32x4 h3 = *(const f32x4*)&hs[(rb + 3) * NH + k];
#pragma unroll
            for (int j = 0; j < 4; ++j) {
                a0 = fmaf(wv[j], h0[j], a0);
                a1 = fmaf(wv[j], h1[j], a1);
                a2 = fmaf(wv[j], h2[j], a2);
                a3 = fmaf(wv[j], h3[j], a3);
            }
        }
        const float bb = bh[col];
        const int orow = (rg << 4) + rb;
        out[(orow + 0) * NC + col] = a0 + bb;
        out[(orow + 1) * NC + col] = a1 + bb;
        out[(orow + 2) * NC + col] = a2 + bb;
        out[(orow + 3) * NC + col] = a3 + bb;
    }
}

extern "C" void kernel_launch(void* const* d_in, const int* in_sizes, int n_in,
                              void* d_out, int out_size, void* d_ws, size_t ws_size,
                              hipStream_t stream)
{
    (void)in_sizes; (void)n_in; (void)out_size; (void)ws_size;
    const float* x     = (const float*)d_in[0];
    const float* Wih   = (const float*)d_in[1];
    const float* Whh   = (const float*)d_in[2];
    const float* bih   = (const float*)d_in[3];
    const float* bhh   = (const float*)d_in[4];
    const float* Whead = (const float*)d_in[5];
    const float* bhead = (const float*)d_in[6];
    float* out = (float*)d_out;

    char* ws = (char*)d_ws;
    unsigned short* hbuf  = (unsigned short*)ws;                  // 2*16*16*512*2B = 512KB
    unsigned int*   flags = (unsigned int*)(ws + 512 * 1024);     // 512 u32 = 2KB
    float*          hT    = (float*)(ws + 512 * 1024 + 2048);     // 512KB

    gru_init_ws<<<2, 256, 0, stream>>>(flags);
    gru_scan<<<128, 256, 0, stream>>>(x, Wih, Whh, bih, bhh, hbuf, hT, flags);
    gru_head<<<dim3(16, 16), 256, 0, stream>>>(hT, Whead, bhead, out);
}